// Round 3
// baseline (140.924 us; speedup 1.0000x reference)
//
#include <hip/hip_runtime.h>
#include <stdint.h>

// ---------------- problem constants ----------------
#define B_SZ 8192
#define LOG8 2.0794415416798357f   // -log(1/8)
#define NTILE 2080                 // 64*65/2 upper-triangular 128x128 tiles

typedef __attribute__((ext_vector_type(8))) short short8;
typedef __attribute__((ext_vector_type(4))) float floatx4;

__device__ inline unsigned short f2bf(float f) {
    unsigned int u = __float_as_uint(f);
    u = (u + 0x7FFFu + ((u >> 16) & 1u)) >> 16;   // RNE
    return (unsigned short)u;
}
__device__ inline float bf2f(unsigned short s) {
    return __uint_as_float(((unsigned int)s) << 16);
}
__device__ inline float wredf(float x) {
#pragma unroll
    for (int o = 32; o; o >>= 1) x += __shfl_down(x, o);
    return x;
}
__device__ inline int wredi(int x) {
#pragma unroll
    for (int o = 32; o; o >>= 1) x += __shfl_down(x, o);
    return x;
}

// acc layout (floats): [0]=task [1]=eff [2]=ent [4..11]=col_sums
//   f32[16..79] = kl partial slots, u32[80..143] = cnt partial slots,
//   u32[144] = done counter
// ---------------- fused prep ----------------
__global__ void prep_all(const float* __restrict__ logits,
                         const int* __restrict__ targets,
                         const float* __restrict__ routing,
                         const float* __restrict__ emb,
                         unsigned short* __restrict__ nrm,
                         unsigned short* __restrict__ lq,
                         unsigned short* __restrict__ pb,
                         float* __restrict__ aprime,
                         float* __restrict__ acc) {
    const int bid = blockIdx.x;
    const int lane = threadIdx.x & 63;

    if (bid < 2048) {
        // ---- embedding normalize -> bf16 (wave per row) ----
        int wave = threadIdx.x >> 6;
        int row = (bid << 2) + wave;
        const float2* e2 = (const float2*)(emb + (size_t)row * 128);
        float2 v = e2[lane];
        float ss = v.x * v.x + v.y * v.y;
        ss = wredf(ss);
        ss = __shfl(ss, 0);
        float inv = rsqrtf(ss);
        ushort2 o;
        o.x = f2bf(v.x * inv);
        o.y = f2bf(v.y * inv);
        ((ushort2*)(nrm + (size_t)row * 128))[lane] = o;
        return;
    }

    // ---- per-row routing prep ----
    int row = ((bid - 2048) << 8) + threadIdx.x;

    const float4* r4 = (const float4*)(routing + (size_t)row * 8);
    float4 va = r4[0], vb = r4[1];
    float v[8] = {va.x, va.y, va.z, va.w, vb.x, vb.y, vb.z, vb.w};

    float mx = v[0];
#pragma unroll
    for (int e = 1; e < 8; ++e) mx = fmaxf(mx, v[e]);
    float ex[8], s = 0.f;
#pragma unroll
    for (int e = 0; e < 8; ++e) { ex[e] = expf(v[e] - mx); s += ex[e]; }
    float ls = logf(s);
    float inv_s = 1.f / s;

    union { unsigned short u[8]; uint4 q; } lu, pu;
    float ap = 0.f;
#pragma unroll
    for (int e = 0; e < 8; ++e) {
        unsigned short pe = f2bf(ex[e] * inv_s);
        unsigned short le = f2bf(v[e] - mx - ls + LOG8);
        pu.u[e] = pe;
        lu.u[e] = le;
        ap += bf2f(pe) * bf2f(le);
    }
    ((uint4*)lq)[row] = lu.q;
    ((uint4*)pb)[row] = pu.q;
    aprime[row] = ap;

    float eff = 0.f, ent = 0.f;
#pragma unroll
    for (int e = 0; e < 8; ++e) {
        if (v[e] < 0.1f) eff += v[e];
        ent += v[e] * logf(v[e] + 1e-8f);
    }

    const float* lg = logits + (size_t)row * 3;
    float a0 = lg[0], a1 = lg[1], a2 = lg[2];
    float mm = fmaxf(a0, fmaxf(a1, a2));
    float lse = mm + logf(expf(a0 - mm) + expf(a1 - mm) + expf(a2 - mm));
    int tg = targets[row];
    float tv = (tg == 0) ? a0 : ((tg == 1) ? a1 : a2);
    float task = lse - tv;

    task = wredf(task);
    eff = wredf(eff);
    ent = wredf(ent);
    float cs[8];
#pragma unroll
    for (int e = 0; e < 8; ++e) cs[e] = wredf(v[e]);

    if (lane == 0) {
        atomicAdd(&acc[0], task);
        atomicAdd(&acc[1], eff);
        atomicAdd(&acc[2], ent);
#pragma unroll
        for (int e = 0; e < 8; ++e) atomicAdd(&acc[4 + e], cs[e]);
    }
}

// ---------------- main: symmetric fused sim-mask + KL + finalize ----------------
// upper-triangular 128x128 tiles; 512 threads (8 waves in 2x4); XOR-swizzled LDS
__global__ __launch_bounds__(512, 4) void tile_sym(
    const unsigned short* __restrict__ nrm,
    const unsigned short* __restrict__ lq,
    const unsigned short* __restrict__ pb,
    const float* __restrict__ aprime,
    float* __restrict__ acc,
    const float* __restrict__ temp,
    float* __restrict__ out) {
    __shared__ uint4 sh[2][128][16];   // 64 KB

    const int t = threadIdx.x;
    const int L = blockIdx.x;

    // triangular decode: bi <= bj
    int bi = (int)((129.0f - sqrtf((float)(16641 - 8 * L))) * 0.5f);
    int T = bi * 64 - ((bi * (bi - 1)) >> 1);
    while (L < T) { --bi; T = bi * 64 - ((bi * (bi - 1)) >> 1); }
    while (L >= T + (64 - bi)) { T += 64 - bi; ++bi; }
    const int bj = bi + (L - T);
    const bool diag = (bi == bj);
    const int iBase = bi << 7, jBase = bj << 7;

    // stage A (and B if off-diagonal): granule g of row r at column g^(r&15)
    const uint4* n4 = (const uint4*)nrm;
#pragma unroll
    for (int it = 0; it < 4; ++it) {
        int c = t + (it << 9);
        int row = c >> 4, g = c & 15;
        int gp = g ^ (row & 15);
        sh[0][row][gp] = n4[((size_t)(iBase + row) << 4) + g];
        if (!diag) sh[1][row][gp] = n4[((size_t)(jBase + row) << 4) + g];
    }

    const int wave = t >> 6, lane = t & 63;
    const int wr = wave >> 2, wc = wave & 3;   // 2 x 4 wave grid
    const int m = lane & 15, q = lane >> 4;

    // cross-term fragments from global (L2-hot):
    //  diag:     A: q0=lq_i            B: q0=p_j            -> cross1
    //  off-diag: A: q0=lq_i, q1=p_i    B: q0=p_j, q1=lq_j   -> cross1+cross2
    const short8 zero8 = (short8){0, 0, 0, 0, 0, 0, 0, 0};
    short8 crA[4], crB[2];
    float apB[2];
    float apA[4][4];
#pragma unroll
    for (int a = 0; a < 4; ++a) {
        int ri = iBase + (wr << 6) + (a << 4) + m;
        short8 v = zero8;
        if (q == 0) v = *(const short8*)&lq[(size_t)ri << 3];
        else if (q == 1 && !diag) v = *(const short8*)&pb[(size_t)ri << 3];
        crA[a] = v;
        if (!diag) {
            float4 a4 = *(const float4*)&aprime[iBase + (wr << 6) + (a << 4) + (q << 2)];
            apA[a][0] = a4.x; apA[a][1] = a4.y; apA[a][2] = a4.z; apA[a][3] = a4.w;
        }
    }
#pragma unroll
    for (int b = 0; b < 2; ++b) {
        int cj = jBase + (wc << 5) + (b << 4) + m;
        short8 v = zero8;
        if (q == 0) v = *(const short8*)&pb[(size_t)cj << 3];
        else if (q == 1 && !diag) v = *(const short8*)&lq[(size_t)cj << 3];
        crB[b] = v;
        apB[b] = aprime[cj];
    }

    __syncthreads();

    const unsigned short* Ab = (const unsigned short*)&sh[0][0][0];
    const unsigned short* Bb = diag ? Ab : (const unsigned short*)&sh[1][0][0];

    floatx4 simacc[4][2];
#pragma unroll
    for (int a = 0; a < 4; ++a)
#pragma unroll
        for (int b = 0; b < 2; ++b) simacc[a][b] = (floatx4){0.f, 0.f, 0.f, 0.f};

    // sim = A . B^T over K=128
#pragma unroll
    for (int ks = 0; ks < 4; ++ks) {
        const int g = (ks << 2) + q;
        short8 af[4], bfr[2];
#pragma unroll
        for (int a = 0; a < 4; ++a) {
            int ra = (wr << 6) + (a << 4) + m;
            af[a] = *(const short8*)&Ab[(ra << 7) + ((g ^ m) << 3)];
        }
#pragma unroll
        for (int b = 0; b < 2; ++b) {
            int rb = (wc << 5) + (b << 4) + m;
            bfr[b] = *(const short8*)&Bb[(rb << 7) + ((g ^ m) << 3)];
        }
#pragma unroll
        for (int a = 0; a < 4; ++a)
#pragma unroll
            for (int b = 0; b < 2; ++b)
                simacc[a][b] = __builtin_amdgcn_mfma_f32_16x16x32_bf16(
                    af[a], bfr[b], simacc[a][b], 0, 0, 0);
    }

    // epilogue: mask + KL
    float klLocal = 0.f;
    int cntLocal = 0;
#pragma unroll
    for (int a = 0; a < 4; ++a) {
        const int gRow0 = iBase + (wr << 6) + (a << 4) + (q << 2);
#pragma unroll
        for (int b = 0; b < 2; ++b) {
            const int gCol = jBase + (wc << 5) + (b << 4) + m;
            floatx4 cr = __builtin_amdgcn_mfma_f32_16x16x32_bf16(
                crA[a], crB[b], (floatx4){0.f, 0.f, 0.f, 0.f}, 0, 0, 0);
            if (diag) {
#pragma unroll
                for (int r = 0; r < 4; ++r) {
                    if ((simacc[a][b][r] > 0.8f) && (gRow0 + r != gCol)) {
                        klLocal += apB[b] - cr[r];
                        cntLocal += 1;
                    }
                }
            } else {
#pragma unroll
                for (int r = 0; r < 4; ++r) {
                    if (simacc[a][b][r] > 0.8f) {
                        klLocal += apA[a][r] + apB[b] - cr[r];
                        cntLocal += 2;
                    }
                }
            }
        }
    }

    klLocal = wredf(klLocal);
    cntLocal = wredi(cntLocal);

    __syncthreads();
    float* redk = (float*)&sh[0][0][0];
    int* redc = (int*)(redk + 8);
    if (lane == 0) { redk[wave] = klLocal; redc[wave] = cntLocal; }
    __syncthreads();

    if (t == 0) {
        float k = 0.f;
        int c = 0;
#pragma unroll
        for (int w = 0; w < 8; ++w) { k += redk[w]; c += redc[w]; }
        int slot = L & 63;
        atomicAdd(&acc[16 + slot], k);
        atomicAdd(&((unsigned int*)acc)[80 + slot], (unsigned int)c);

        __threadfence();
        unsigned int old = atomicAdd(&((unsigned int*)acc)[144], 1u);
        if (old == NTILE - 1) {
            // last block: finalize (agent-scope loads; cross-XCD safe)
            __threadfence();
            float ks = 0.f;
            unsigned int cs = 0;
#pragma unroll
            for (int w = 0; w < 64; ++w) {
                ks += __hip_atomic_load(&acc[16 + w], __ATOMIC_RELAXED,
                                        __HIP_MEMORY_SCOPE_AGENT);
                cs += __hip_atomic_load(&((unsigned int*)acc)[80 + w],
                                        __ATOMIC_RELAXED, __HIP_MEMORY_SCOPE_AGENT);
            }
            const float invB = 1.f / (float)B_SZ;
            float task = __hip_atomic_load(&acc[0], __ATOMIC_RELAXED,
                                           __HIP_MEMORY_SCOPE_AGENT) * invB;
            float eff = 0.05f * __hip_atomic_load(&acc[1], __ATOMIC_RELAXED,
                                                  __HIP_MEMORY_SCOPE_AGENT) * invB;
            float entl = 0.01f * __hip_atomic_load(&acc[2], __ATOMIC_RELAXED,
                                                   __HIP_MEMORY_SCOPE_AGENT) * invB;
            float cons = 0.1f * (cs > 0 ? ks / (float)cs : 0.f);
            float u[8], mean = 0.f;
            for (int e = 0; e < 8; ++e) {
                u[e] = __hip_atomic_load(&acc[4 + e], __ATOMIC_RELAXED,
                                         __HIP_MEMORY_SCOPE_AGENT) * invB;
                mean += u[e];
            }
            mean *= 0.125f;
            float var = 0.f;
            for (int e = 0; e < 8; ++e) { float d = u[e] - mean; var += d * d; }
            var *= (1.f / 7.f);            // unbiased (ddof=1)
            float lb = 0.1f * var * 64.f;  // * E^2
            float tt = temp[0] - 1.f;
            out[0] = task + lb + eff + cons + entl + 0.01f * tt * tt;
        }
    }
}

// ---------------- launch ----------------
extern "C" void kernel_launch(void* const* d_in, const int* in_sizes, int n_in,
                              void* d_out, int out_size, void* d_ws, size_t ws_size,
                              hipStream_t stream) {
    const float* logits = (const float*)d_in[0];
    const int* targets = (const int*)d_in[1];
    const float* routing = (const float*)d_in[2];
    const float* emb = (const float*)d_in[3];
    const float* temp = (const float*)d_in[4];

    char* ws = (char*)d_ws;
    unsigned short* nrm = (unsigned short*)ws;               // 2097152 B
    unsigned short* lq = (unsigned short*)(ws + 2097152);    // 131072
    unsigned short* pb = (unsigned short*)(ws + 2228224);    // 131072
    float* aprime = (float*)(ws + 2359296);                  // 32768
    float* acc = (float*)(ws + 2392064);                     // 1024

    hipMemsetAsync(acc, 0, 1024, stream);
    prep_all<<<2080, 256, 0, stream>>>(logits, targets, routing, emb,
                                       nrm, lq, pb, aprime, acc);
    tile_sym<<<NTILE, 512, 0, stream>>>(nrm, lq, pb, aprime, acc, temp,
                                        (float*)d_out);
}

// Round 4
// 116.480 us; speedup vs baseline: 1.2099x; 1.2099x over previous
//
#include <hip/hip_runtime.h>
#include <stdint.h>

// ---------------- problem constants ----------------
#define B_SZ 8192
#define LOG8 2.0794415416798357f   // -log(1/8)
#define NTILE 2080                 // 64*65/2 upper-triangular 128x128 tiles

typedef __attribute__((ext_vector_type(8))) short short8;
typedef __attribute__((ext_vector_type(4))) float floatx4;

__device__ inline unsigned short f2bf(float f) {
    unsigned int u = __float_as_uint(f);
    u = (u + 0x7FFFu + ((u >> 16) & 1u)) >> 16;   // RNE
    return (unsigned short)u;
}
__device__ inline float bf2f(unsigned short s) {
    return __uint_as_float(((unsigned int)s) << 16);
}
__device__ inline float wredf(float x) {
#pragma unroll
    for (int o = 32; o; o >>= 1) x += __shfl_down(x, o);
    return x;
}
__device__ inline int wredi(int x) {
#pragma unroll
    for (int o = 32; o; o >>= 1) x += __shfl_down(x, o);
    return x;
}

// acc layout (floats): [0]=task [1]=eff [2]=ent [4..11]=col_sums
//   f32[16..79] = kl partial slots, u32[80..143] = cnt partial slots
// ---------------- fused prep ----------------
__global__ void prep_all(const float* __restrict__ logits,
                         const int* __restrict__ targets,
                         const float* __restrict__ routing,
                         const float* __restrict__ emb,
                         unsigned short* __restrict__ nrm,
                         unsigned short* __restrict__ lq,
                         unsigned short* __restrict__ pb,
                         float* __restrict__ aprime,
                         float* __restrict__ acc) {
    const int bid = blockIdx.x;
    const int lane = threadIdx.x & 63;

    if (bid < 2048) {
        // ---- embedding normalize -> bf16 (wave per row) ----
        int wave = threadIdx.x >> 6;
        int row = (bid << 2) + wave;
        const float2* e2 = (const float2*)(emb + (size_t)row * 128);
        float2 v = e2[lane];
        float ss = v.x * v.x + v.y * v.y;
        ss = wredf(ss);
        ss = __shfl(ss, 0);
        float inv = rsqrtf(ss);
        ushort2 o;
        o.x = f2bf(v.x * inv);
        o.y = f2bf(v.y * inv);
        ((ushort2*)(nrm + (size_t)row * 128))[lane] = o;
        return;
    }

    // ---- per-row routing prep ----
    int row = ((bid - 2048) << 8) + threadIdx.x;

    const float4* r4 = (const float4*)(routing + (size_t)row * 8);
    float4 va = r4[0], vb = r4[1];
    float v[8] = {va.x, va.y, va.z, va.w, vb.x, vb.y, vb.z, vb.w};

    float mx = v[0];
#pragma unroll
    for (int e = 1; e < 8; ++e) mx = fmaxf(mx, v[e]);
    float ex[8], s = 0.f;
#pragma unroll
    for (int e = 0; e < 8; ++e) { ex[e] = expf(v[e] - mx); s += ex[e]; }
    float ls = logf(s);
    float inv_s = 1.f / s;

    union { unsigned short u[8]; uint4 q; } lu, pu;
    float ap = 0.f;
#pragma unroll
    for (int e = 0; e < 8; ++e) {
        unsigned short pe = f2bf(ex[e] * inv_s);
        unsigned short le = f2bf(v[e] - mx - ls + LOG8);
        pu.u[e] = pe;
        lu.u[e] = le;
        ap += bf2f(pe) * bf2f(le);
    }
    ((uint4*)lq)[row] = lu.q;
    ((uint4*)pb)[row] = pu.q;
    aprime[row] = ap;

    float eff = 0.f, ent = 0.f;
#pragma unroll
    for (int e = 0; e < 8; ++e) {
        if (v[e] < 0.1f) eff += v[e];
        ent += v[e] * logf(v[e] + 1e-8f);
    }

    const float* lg = logits + (size_t)row * 3;
    float a0 = lg[0], a1 = lg[1], a2 = lg[2];
    float mm = fmaxf(a0, fmaxf(a1, a2));
    float lse = mm + logf(expf(a0 - mm) + expf(a1 - mm) + expf(a2 - mm));
    int tg = targets[row];
    float tv = (tg == 0) ? a0 : ((tg == 1) ? a1 : a2);
    float task = lse - tv;

    task = wredf(task);
    eff = wredf(eff);
    ent = wredf(ent);
    float cs[8];
#pragma unroll
    for (int e = 0; e < 8; ++e) cs[e] = wredf(v[e]);

    if (lane == 0) {
        atomicAdd(&acc[0], task);
        atomicAdd(&acc[1], eff);
        atomicAdd(&acc[2], ent);
#pragma unroll
        for (int e = 0; e < 8; ++e) atomicAdd(&acc[4 + e], cs[e]);
    }
}

// ---------------- main: symmetric fused sim-mask + KL ----------------
// upper-triangular 128x128 tiles; 512 threads (8 waves in 2x4); XOR-swizzled LDS
// branch-free staging & cross loads; no fences; separate finalize kernel.
__global__ __launch_bounds__(512, 4) void tile_sym(
    const unsigned short* __restrict__ nrm,
    const unsigned short* __restrict__ lq,
    const unsigned short* __restrict__ pb,
    const float* __restrict__ aprime,
    float* __restrict__ acc) {
    __shared__ uint4 sh[2][128][16];   // 64 KB

    const int t = threadIdx.x;
    const int L = blockIdx.x;

    // triangular decode: bi <= bj
    int bi = (int)((129.0f - sqrtf((float)(16641 - 8 * L))) * 0.5f);
    int T = bi * 64 - ((bi * (bi - 1)) >> 1);
    while (L < T) { --bi; T = bi * 64 - ((bi * (bi - 1)) >> 1); }
    while (L >= T + (64 - bi)) { T += 64 - bi; ++bi; }
    const int bj = bi + (L - T);
    const bool diag = (bi == bj);
    const int iBase = bi << 7, jBase = bj << 7;

    // stage A and B unconditionally (diag stages B=A; 64 blocks' waste is nil)
    const uint4* n4 = (const uint4*)nrm;
#pragma unroll
    for (int it = 0; it < 4; ++it) {
        int c = t + (it << 9);
        int row = c >> 4, g = c & 15;
        int gp = g ^ (row & 15);
        uint4 va = n4[((size_t)(iBase + row) << 4) + g];
        uint4 vb = n4[((size_t)(jBase + row) << 4) + g];
        sh[0][row][gp] = va;
        sh[1][row][gp] = vb;
    }

    const int wave = t >> 6, lane = t & 63;
    const int wr = wave >> 2, wc = wave & 3;   // 2 x 4 wave grid
    const int m = lane & 15, q = lane >> 4;

    // cross-term fragments from global (L2-hot), branch-free:
    //  A: q0 = lq_i, q1 = p_i   B: q0 = p_j, q1 = lq_j   (q1 zeroed on diag)
    const short8 zero8 = (short8){0, 0, 0, 0, 0, 0, 0, 0};
    short8 crA[4], crB[2];
    float apB[2];
    float apA[4][4];
    const unsigned short* baseA = q ? pb : lq;
    const unsigned short* baseB = q ? lq : pb;
#pragma unroll
    for (int a = 0; a < 4; ++a) {
        int ri = iBase + (wr << 6) + (a << 4) + m;
        short8 v = zero8;
        if (q < 2) v = *(const short8*)&baseA[(size_t)ri << 3];
        if (diag && q == 1) v = zero8;
        crA[a] = v;
        float4 a4 = *(const float4*)&aprime[iBase + (wr << 6) + (a << 4) + (q << 2)];
        apA[a][0] = a4.x; apA[a][1] = a4.y; apA[a][2] = a4.z; apA[a][3] = a4.w;
    }
#pragma unroll
    for (int b = 0; b < 2; ++b) {
        int cj = jBase + (wc << 5) + (b << 4) + m;
        short8 v = zero8;
        if (q < 2) v = *(const short8*)&baseB[(size_t)cj << 3];
        if (diag && q == 1) v = zero8;
        crB[b] = v;
        apB[b] = aprime[cj];
    }

    __syncthreads();

    const unsigned short* Ab = (const unsigned short*)&sh[0][0][0];
    const unsigned short* Bb = (const unsigned short*)&sh[1][0][0];

    floatx4 simacc[4][2];
#pragma unroll
    for (int a = 0; a < 4; ++a)
#pragma unroll
        for (int b = 0; b < 2; ++b) simacc[a][b] = (floatx4){0.f, 0.f, 0.f, 0.f};

    // sim = A . B^T over K=128
#pragma unroll
    for (int ks = 0; ks < 4; ++ks) {
        const int g = (ks << 2) + q;
        short8 af[4], bfr[2];
#pragma unroll
        for (int a = 0; a < 4; ++a) {
            int ra = (wr << 6) + (a << 4) + m;
            af[a] = *(const short8*)&Ab[(ra << 7) + ((g ^ m) << 3)];
        }
#pragma unroll
        for (int b = 0; b < 2; ++b) {
            int rb = (wc << 5) + (b << 4) + m;
            bfr[b] = *(const short8*)&Bb[(rb << 7) + ((g ^ m) << 3)];
        }
#pragma unroll
        for (int a = 0; a < 4; ++a)
#pragma unroll
            for (int b = 0; b < 2; ++b)
                simacc[a][b] = __builtin_amdgcn_mfma_f32_16x16x32_bf16(
                    af[a], bfr[b], simacc[a][b], 0, 0, 0);
    }

    // epilogue: mask + KL
    float klLocal = 0.f;
    int cntLocal = 0;
#pragma unroll
    for (int a = 0; a < 4; ++a) {
        const int gRow0 = iBase + (wr << 6) + (a << 4) + (q << 2);
#pragma unroll
        for (int b = 0; b < 2; ++b) {
            const int gCol = jBase + (wc << 5) + (b << 4) + m;
            floatx4 cr = __builtin_amdgcn_mfma_f32_16x16x32_bf16(
                crA[a], crB[b], (floatx4){0.f, 0.f, 0.f, 0.f}, 0, 0, 0);
            if (diag) {
#pragma unroll
                for (int r = 0; r < 4; ++r) {
                    if ((simacc[a][b][r] > 0.8f) && (gRow0 + r != gCol)) {
                        klLocal += apB[b] - cr[r];
                        cntLocal += 1;
                    }
                }
            } else {
#pragma unroll
                for (int r = 0; r < 4; ++r) {
                    if (simacc[a][b][r] > 0.8f) {
                        klLocal += apA[a][r] + apB[b] - cr[r];
                        cntLocal += 2;
                    }
                }
            }
        }
    }

    klLocal = wredf(klLocal);
    cntLocal = wredi(cntLocal);

    __syncthreads();
    float* redk = (float*)&sh[0][0][0];
    int* redc = (int*)(redk + 8);
    if (lane == 0) { redk[wave] = klLocal; redc[wave] = cntLocal; }
    __syncthreads();

    if (t == 0) {
        float k = 0.f;
        int c = 0;
#pragma unroll
        for (int w = 0; w < 8; ++w) { k += redk[w]; c += redc[w]; }
        int slot = L & 63;
        atomicAdd(&acc[16 + slot], k);
        atomicAdd(&((unsigned int*)acc)[80 + slot], (unsigned int)c);
    }
}

// ---------------- finalize (1 block x 64) ----------------
__global__ void finalize_k(const float* __restrict__ acc,
                           const float* __restrict__ temp,
                           float* __restrict__ out) {
    int lane = threadIdx.x;
    float k = acc[16 + lane];
    int c = (int)((const unsigned int*)acc)[80 + lane];
    k = wredf(k);
    c = wredi(c);
    if (lane == 0) {
        const float invB = 1.f / (float)B_SZ;
        float task = acc[0] * invB;
        float eff = 0.05f * acc[1] * invB;
        float entl = 0.01f * acc[2] * invB;
        float cons = 0.1f * (c > 0 ? k / (float)c : 0.f);
        float u[8], mean = 0.f;
        for (int e = 0; e < 8; ++e) { u[e] = acc[4 + e] * invB; mean += u[e]; }
        mean *= 0.125f;
        float var = 0.f;
        for (int e = 0; e < 8; ++e) { float d = u[e] - mean; var += d * d; }
        var *= (1.f / 7.f);                // unbiased (ddof=1)
        float lb = 0.1f * var * 64.f;      // * E^2
        float tt = temp[0] - 1.f;
        out[0] = task + lb + eff + cons + entl + 0.01f * tt * tt;
    }
}

// ---------------- launch ----------------
extern "C" void kernel_launch(void* const* d_in, const int* in_sizes, int n_in,
                              void* d_out, int out_size, void* d_ws, size_t ws_size,
                              hipStream_t stream) {
    const float* logits = (const float*)d_in[0];
    const int* targets = (const int*)d_in[1];
    const float* routing = (const float*)d_in[2];
    const float* emb = (const float*)d_in[3];
    const float* temp = (const float*)d_in[4];

    char* ws = (char*)d_ws;
    unsigned short* nrm = (unsigned short*)ws;               // 2097152 B
    unsigned short* lq = (unsigned short*)(ws + 2097152);    // 131072
    unsigned short* pb = (unsigned short*)(ws + 2228224);    // 131072
    float* aprime = (float*)(ws + 2359296);                  // 32768
    float* acc = (float*)(ws + 2392064);                     // 1024

    hipMemsetAsync(acc, 0, 1024, stream);
    prep_all<<<2080, 256, 0, stream>>>(logits, targets, routing, emb,
                                       nrm, lq, pb, aprime, acc);
    tile_sym<<<NTILE, 512, 0, stream>>>(nrm, lq, pb, aprime, acc);
    finalize_k<<<1, 64, 0, stream>>>(acc, temp, (float*)d_out);
}